// Round 7
// baseline (599.610 us; speedup 1.0000x reference)
//
#include <hip/hip_runtime.h>
#include <math.h>

// ---------------------------------------------------------------------------
// AttnModel3: B=256, N=64, F=64, S=130.
//   q_f(n) = ( U_f + c_f(n)*W[129,:] - m_f(n)*A_f ) * inv_f(n) + B_f
// R7 = R6 with pk2() as inline-asm v_cvt_pk_bf16_f32 (no builtin on gfx950;
// __hip_bfloat162 isn't bit_cast-able). 1024-thread blocks (16 waves),
// 4 barriers/n, AW transposed in LDS, per-b U staged in LDS.
// ---------------------------------------------------------------------------

typedef __attribute__((ext_vector_type(4))) float f32x4;
typedef __attribute__((ext_vector_type(8))) short bf16x8;

#define EPSF 1e-6f
#define INVS 0.0877058019307029f /* 1/sqrt(130) */

__device__ __forceinline__ unsigned short f2bf(float f) {
  unsigned int u = __builtin_bit_cast(unsigned int, f);
  u += 0x7FFFu + ((u >> 16) & 1u);
  return (unsigned short)(u >> 16);
}
__device__ __forceinline__ float b2f(unsigned short s) {
  unsigned int u = ((unsigned int)s) << 16;
  return __builtin_bit_cast(float, u);
}
__device__ __forceinline__ unsigned int pk2(float a, float b) {
  unsigned int r;
  asm("v_cvt_pk_bf16_f32 %0, %1, %2" : "=v"(r) : "v"(a), "v"(b));
  return r;
}

// ---------------- kernel 0: global precomputes (bf16 packed) ----------------
__global__ __launch_bounds__(256) void k0(
    const float* __restrict__ alpha1, const float* __restrict__ beta1,
    const float* __restrict__ alpha2, const float* __restrict__ beta2,
    const float* __restrict__ Wq, const float* __restrict__ bq,
    const float* __restrict__ Wk, const float* __restrict__ bk,
    const float* __restrict__ Wv, const float* __restrict__ bv,
    const float* __restrict__ Wlin, const float* __restrict__ blin,
    unsigned short* __restrict__ ABqk, unsigned short* __restrict__ ABv,
    unsigned short* __restrict__ AWt, float* __restrict__ Paw, float* __restrict__ Ccw)
{
  __shared__ float sbuf[64 * 132];
  __shared__ float Wbuf[130 * 144];
  int blk = blockIdx.x, tid = threadIdx.x;
  if (blk < 6) {
    int m = blk >> 1, isB = blk & 1;
    const float* src  = isB ? beta1 : alpha1;
    const float* W    = (m == 0) ? Wq : (m == 1) ? Wk : Wv;
    const float* bias = (m == 0) ? bq : (m == 1) ? bk : bv;
    for (int e = tid; e < 8320; e += 256) { int f = e / 130, s = e - f * 130; sbuf[f * 132 + s] = src[e]; }
    for (int e = tid; e < 16900; e += 256) { int s = e / 130, t = e - s * 130; Wbuf[s * 144 + t] = W[e]; }
    __syncthreads();
    int ty = tid >> 4, tx = tid & 15;
    float acc[4][9] = {};
    for (int s = 0; s < 130; ++s) {
      float g0 = sbuf[(ty * 4 + 0) * 132 + s];
      float g1 = sbuf[(ty * 4 + 1) * 132 + s];
      float g2 = sbuf[(ty * 4 + 2) * 132 + s];
      float g3 = sbuf[(ty * 4 + 3) * 132 + s];
#pragma unroll
      for (int c = 0; c < 9; ++c) {
        float wv = Wbuf[s * 144 + tx + 16 * c];
        acc[0][c] += g0 * wv; acc[1][c] += g1 * wv;
        acc[2][c] += g2 * wv; acc[3][c] += g3 * wv;
      }
    }
#pragma unroll
    for (int i = 0; i < 4; ++i)
      for (int c = 0; c < 9; ++c) {
        int t = tx + 16 * c;
        if (t < 136) {
          float val = (t < 130) ? (acc[i][c] + (isB ? bias[t] : 0.f)) : 0.f;
          unsigned short v16 = f2bf(val);
          int f = ty * 4 + i;
          if (m == 2) ABv[t * 128 + isB * 64 + f] = v16;                       // [t][{A,B}][f]
          else        ABqk[(m * 64 + f) * 272 + (t >> 3) * 16 + isB * 8 + (t & 7)] = v16;
        }
      }
  } else if (blk == 6) {
    if (tid < 64) {
      int f = tid;
      float pa = 0.f, cc = 0.f;
      for (int s = 0; s < 130; ++s) {
        float wl = Wlin[f * 130 + s];
        float aw = alpha2[f * 130 + s] * wl;
        AWt[s * 72 + f] = f2bf(aw);   // transposed [col][row]
        pa += aw;
        cc += beta2[f * 130 + s] * wl;
      }
      for (int s = 130; s < 144; ++s) AWt[s * 72 + f] = 0;
      Paw[f] = pa;
#pragma unroll
      for (int msk = 1; msk <= 32; msk <<= 1) cc += __shfl_xor(cc, msk, 64);
      if (f == 0) Ccw[0] = cc + blin[0];
    }
  }
}

// ---------------- kernel 1: per-b U (bf16), S1, S2 ----------------
__global__ __launch_bounds__(256) void k1(
    const float* __restrict__ h1, const float* __restrict__ h2,
    const float* __restrict__ sp, const float* __restrict__ alpha1,
    const float* __restrict__ Wq, const float* __restrict__ Wk, const float* __restrict__ Wv,
    unsigned short* __restrict__ UqkB, unsigned short* __restrict__ UvB,
    float* __restrict__ S1g, float* __restrict__ S2g)
{
  __shared__ float gbuf[64 * 132];
  __shared__ float Wbuf[130 * 144];
  __shared__ float ps[2][256];
  int b = blockIdx.x, tid = threadIdx.x;
  float s1 = 0.f, s2 = 0.f;
  for (int idx = tid; idx < 8256; idx += 256) {  // 129*64
    int s = idx >> 6, f = idx & 63;
    float x = (s < 64)  ? h1[((size_t)(b * 64 + s)) * 64 + f]
            : (s < 128) ? h2[((size_t)(b * 64 + (s - 64))) * 64 + f]
                        : sp[b * 64 + f];
    gbuf[f * 132 + s] = alpha1[f * 130 + s] * x;
    s1 += x; s2 += x * x;
  }
  ps[0][tid] = s1; ps[1][tid] = s2;
  __syncthreads();
  if (tid < 64) {
    S1g[b * 64 + tid] = ps[0][tid] + ps[0][tid + 64] + ps[0][tid + 128] + ps[0][tid + 192];
    S2g[b * 64 + tid] = ps[1][tid] + ps[1][tid + 64] + ps[1][tid + 128] + ps[1][tid + 192];
  }
  int ty = tid >> 4, tx = tid & 15;
  for (int m = 0; m < 3; ++m) {
    const float* W = (m == 0) ? Wq : (m == 1) ? Wk : Wv;
    __syncthreads();
    for (int e = tid; e < 16900; e += 256) { int s = e / 130, t = e - s * 130; Wbuf[s * 144 + t] = W[e]; }
    __syncthreads();
    float acc[4][9] = {};
    for (int s = 0; s < 129; ++s) {  // K = 129 (col 129 handled per-n)
      float g0 = gbuf[(ty * 4 + 0) * 132 + s];
      float g1 = gbuf[(ty * 4 + 1) * 132 + s];
      float g2 = gbuf[(ty * 4 + 2) * 132 + s];
      float g3 = gbuf[(ty * 4 + 3) * 132 + s];
#pragma unroll
      for (int c = 0; c < 9; ++c) {
        float wv = Wbuf[s * 144 + tx + 16 * c];
        acc[0][c] += g0 * wv; acc[1][c] += g1 * wv;
        acc[2][c] += g2 * wv; acc[3][c] += g3 * wv;
      }
    }
#pragma unroll
    for (int i = 0; i < 4; ++i)
      for (int c = 0; c < 9; ++c) {
        int t = tx + 16 * c;
        if (t < 136) {
          unsigned short v16 = f2bf((t < 130) ? acc[i][c] : 0.f);
          int f = ty * 4 + i;
          if (m == 2) UvB[((size_t)b * 136 + t) * 64 + f] = v16;               // [t][f]
          else        UqkB[(((size_t)b * 2 + m) * 64 + f) * 136 + t] = v16;    // [f][t]
        }
      }
  }
}

// ---------------- kernel 2: per-b attention, 1024 threads ----------------
__global__ __launch_bounds__(1024, 4) void k2(
    const float* __restrict__ h2, const float* __restrict__ alpha1,
    const unsigned short* __restrict__ UqkB, const unsigned short* __restrict__ UvB,
    const unsigned short* __restrict__ ABqk, const unsigned short* __restrict__ ABv,
    const unsigned short* __restrict__ AWt,
    const float* __restrict__ S1g, const float* __restrict__ S2g,
    const float* __restrict__ Paw, const float* __restrict__ Ccw,
    const float* __restrict__ Wq, const float* __restrict__ Wk, const float* __restrict__ Wv,
    float* __restrict__ out)
{
  __shared__ __align__(16) unsigned short qb[64 * 168];        // 21504 B
  __shared__ __align__(16) unsigned short kb[64 * 168];        // 21504 B
  __shared__ __align__(16) unsigned short vT[144 * 72];        // 20736 B
  __shared__ __align__(16) unsigned short pb[64 * 72];         //  9216 B
  __shared__ __align__(16) unsigned short uqk_l[2 * 64 * 136]; // 34816 B
  __shared__ __align__(16) unsigned short uv_l[136 * 72];      // 19584 B
  __shared__ __align__(16) unsigned short AW_T[144 * 72];      // 20736 B
  __shared__ __align__(16) float w129l[3][136];                //  1632 B
  __shared__ float S1l[64], S2l[64], ael[64];
  __shared__ float mrow[64], irow[64], crow[64];
  __shared__ float smaxl[16][16];
  __shared__ float ssuml[16][16];
  __shared__ float stred[16][16][4];
  // total ~157.4 KB -> 1 block/CU, 16 waves = 4 waves/SIMD

  int b = blockIdx.x;
  int tid = threadIdx.x;
  int w = tid >> 6, l = tid & 63, l15 = l & 15, l4 = l >> 4;
  int bi = w >> 2, bj = w & 3;   // QK^T tile (row band, col band); PV: sfj = bj

  // ---- one-time block setup ----
  if (tid < 136) {
    w129l[0][tid] = (tid < 130) ? Wq[129 * 130 + tid] : 0.f;
    w129l[1][tid] = (tid < 130) ? Wk[129 * 130 + tid] : 0.f;
    w129l[2][tid] = (tid < 130) ? Wv[129 * 130 + tid] : 0.f;
  }
  if (tid >= 256 && tid < 320) {
    int f = tid - 256;
    S1l[f] = S1g[b * 64 + f];
    S2l[f] = S2g[b * 64 + f];
    ael[f] = alpha1[f * 130 + 129];
  }
  {
    const uint4* src = (const uint4*)(UqkB + ((size_t)b * 2) * 64 * 136);
    uint4* dst = (uint4*)uqk_l;
    for (int i = tid; i < 2176; i += 1024) dst[i] = src[i];
  }
  {
    const unsigned short* src = UvB + (size_t)b * 136 * 64;
    for (int i = tid; i < 136 * 8; i += 1024) {
      int t = i >> 3, c = i & 7;
      *(uint4*)&uv_l[t * 72 + c * 8] = *(const uint4*)&src[t * 64 + c * 8];
    }
  }
  {
    const uint4* src = (const uint4*)AWt;
    uint4* dst = (uint4*)AW_T;
    for (int i = tid; i < 1296; i += 1024) dst[i] = src[i];
  }
  for (int i = tid; i < 64 * 24; i += 1024) {  // zero MFMA K-tails [136,160)
    int f = i / 24, t = 136 + (i - f * 24);
    qb[f * 168 + t] = 0; kb[f * 168 + t] = 0;
  }
  for (int i = tid; i < 14 * 72; i += 1024) vT[130 * 72 + i] = 0;  // zero pad rows
  float ccv = Ccw[0];
  __syncthreads();

  auto coeffs = [&](int nn) {  // caller guards tid < 64
    float a  = h2[((size_t)(b * 64 + nn)) * 64 + tid];
    float m  = (S1l[tid] + a) * (1.f / 130.f);
    float e2 = (S2l[tid] + a * a) * (1.f / 130.f);
    float sd = sqrtf(fmaxf(e2 - m * m, 0.f));
    mrow[tid] = m;
    irow[tid] = 1.f / (sd + EPSF);
    crow[tid] = ael[tid] * a;
  };

  auto genv = [&](int t, int f8) {
    float wv = w129l[2][t];
    bf16x8 uu = *(const bf16x8*)(uv_l + t * 72 + f8 * 8);
    bf16x8 aa = *(const bf16x8*)(ABv + t * 128 + f8 * 8);
    bf16x8 bb = *(const bf16x8*)(ABv + t * 128 + 64 + f8 * 8);
    f32x4 m0 = *(const f32x4*)&mrow[f8 * 8], m1 = *(const f32x4*)&mrow[f8 * 8 + 4];
    f32x4 i0 = *(const f32x4*)&irow[f8 * 8], i1 = *(const f32x4*)&irow[f8 * 8 + 4];
    f32x4 c0 = *(const f32x4*)&crow[f8 * 8], c1 = *(const f32x4*)&crow[f8 * 8 + 4];
    float v[8];
#pragma unroll
    for (int e = 0; e < 4; ++e)
      v[e] = (b2f(uu[e]) + c0[e] * wv - m0[e] * b2f(aa[e])) * i0[e] + b2f(bb[e]);
#pragma unroll
    for (int e = 0; e < 4; ++e)
      v[4 + e] = (b2f(uu[4 + e]) + c1[e] * wv - m1[e] * b2f(aa[4 + e])) * i1[e] + b2f(bb[4 + e]);
    uint4 ov;
    ov.x = pk2(v[0], v[1]); ov.y = pk2(v[2], v[3]);
    ov.z = pk2(v[4], v[5]); ov.w = pk2(v[6], v[7]);
    *(uint4*)&vT[t * 72 + f8 * 8] = ov;
  };

  if (tid < 64) coeffs(0);
  __syncthreads();

  for (int n = 0; n < 64; ++n) {
    // ---- regen q (tid<512) / k (tid>=512) ----
    {
      int isK = tid >> 9;
      int t5 = tid & 511;
      int f = t5 >> 3, j = t5 & 7;
      float m = mrow[f], inv = irow[f], c = crow[f];
      const unsigned short* ub = uqk_l + (isK * 64 + f) * 136;
      const unsigned short* ab = ABqk + (isK * 64 + f) * 272;
      const float* wl = w129l[isK];
      unsigned short* dst = (isK ? kb : qb) + f * 168;
#pragma unroll
      for (int kg = 0; kg < 2; ++kg) {
        int g = j + kg * 8;
        bf16x8 uu = *(const bf16x8*)(ub + g * 8);
        bf16x8 aa = *(const bf16x8*)(ab + g * 16);
        bf16x8 bb = *(const bf16x8*)(ab + g * 16 + 8);
        f32x4 w0 = *(const f32x4*)&wl[g * 8];
        f32x4 w1 = *(const f32x4*)&wl[g * 8 + 4];
        float v[8];
#pragma unroll
        for (int e = 0; e < 4; ++e)
          v[e] = (b2f(uu[e]) + c * w0[e] - m * b2f(aa[e])) * inv + b2f(bb[e]);
#pragma unroll
        for (int e = 0; e < 4; ++e)
          v[4 + e] = (b2f(uu[4 + e]) + c * w1[e] - m * b2f(aa[4 + e])) * inv + b2f(bb[4 + e]);
        uint4 ov;
        ov.x = pk2(v[0], v[1]); ov.y = pk2(v[2], v[3]);
        ov.z = pk2(v[4], v[5]); ov.w = pk2(v[6], v[7]);
        *(uint4*)(dst + g * 8) = ov;
      }
      if (j == 0) {  // group 16: t = 128..135 (t>=130 operands zero)
        const int g = 16;
        bf16x8 uu = *(const bf16x8*)(ub + g * 8);
        bf16x8 aa = *(const bf16x8*)(ab + g * 16);
        bf16x8 bb = *(const bf16x8*)(ab + g * 16 + 8);
        f32x4 w0 = *(const f32x4*)&wl[g * 8];
        f32x4 w1 = *(const f32x4*)&wl[g * 8 + 4];
        float v[8];
#pragma unroll
        for (int e = 0; e < 4; ++e)
          v[e] = (b2f(uu[e]) + c * w0[e] - m * b2f(aa[e])) * inv + b2f(bb[e]);
#pragma unroll
        for (int e = 0; e < 4; ++e)
          v[4 + e] = (b2f(uu[4 + e]) + c * w1[e] - m * b2f(aa[4 + e])) * inv + b2f(bb[e + 4]);
        uint4 ov;
        ov.x = pk2(v[0], v[1]); ov.y = pk2(v[2], v[3]);
        ov.z = pk2(v[4], v[5]); ov.w = pk2(v[6], v[7]);
        *(uint4*)(dst + g * 8) = ov;
      }
    }
    // ---- regen v^T: 1040 octets over 1024 threads ----
    genv(tid >> 3, tid & 7);
    if (tid < 16) genv(128 + (tid >> 3), tid & 7);
    __syncthreads();  // A

    // ---- sim = q k^T: wave w -> 16x16 tile (bi, bj) ----
    f32x4 sacc = {0.f, 0.f, 0.f, 0.f};
    {
      const unsigned short* qrow = &qb[(bi * 16 + l15) * 168 + l4 * 8];
      const unsigned short* krow = &kb[(bj * 16 + l15) * 168 + l4 * 8];
#pragma unroll
      for (int kk = 0; kk < 5; ++kk) {
        bf16x8 avv = *(const bf16x8*)&qrow[kk * 32];
        bf16x8 bvv = *(const bf16x8*)&krow[kk * 32];
        sacc = __builtin_amdgcn_mfma_f32_16x16x32_bf16(avv, bvv, sacc, 0, 0, 0);
      }
    }
    // ---- local softmax stats (single store + single barrier) ----
    float lm[4], prob[4];
#pragma unroll
    for (int r = 0; r < 4; ++r) {
      float mx = sacc[r];
#pragma unroll
      for (int msk = 1; msk <= 8; msk <<= 1) mx = fmaxf(mx, __shfl_xor(mx, msk, 64));
      lm[r] = mx;
      float e = __expf((sacc[r] - mx) * INVS);
      prob[r] = e;
      float ps = e;
#pragma unroll
      for (int msk = 1; msk <= 8; msk <<= 1) ps += __shfl_xor(ps, msk, 64);
      if (l15 == 0) { smaxl[w][l4 * 4 + r] = mx; ssuml[w][l4 * 4 + r] = ps; }
    }
    __syncthreads();  // B

    // ---- combine 4 col-bands, write normalized p ----
#pragma unroll
    for (int r = 0; r < 4; ++r) {
      int row16 = l4 * 4 + r;
      float m0 = smaxl[bi * 4 + 0][row16], m1 = smaxl[bi * 4 + 1][row16];
      float m2 = smaxl[bi * 4 + 2][row16], m3 = smaxl[bi * 4 + 3][row16];
      float gm = fmaxf(fmaxf(m0, m1), fmaxf(m2, m3));
      float gs = ssuml[bi * 4 + 0][row16] * __expf((m0 - gm) * INVS)
               + ssuml[bi * 4 + 1][row16] * __expf((m1 - gm) * INVS)
               + ssuml[bi * 4 + 2][row16] * __expf((m2 - gm) * INVS)
               + ssuml[bi * 4 + 3][row16] * __expf((m3 - gm) * INVS);
      float pr = prob[r] * (__expf((lm[r] - gm) * INVS) / gs);
      pb[(bi * 16 + row16) * 72 + bj * 16 + l15] = f2bf(pr);
    }
    __syncthreads();  // C

    // ---- ao = p v: wave (bi, sfj): sf = sfj, sfj+4 (+8 if sfj==0) ----
    f32x4 ao0 = {0.f, 0.f, 0.f, 0.f}, ao1 = ao0, ao2 = ao0;
    {
      const unsigned short* prow = &pb[(bi * 16 + l15) * 72 + l4 * 8];
#pragma unroll
      for (int kk = 0; kk < 2; ++kk) {
        bf16x8 avv = *(const bf16x8*)&prow[kk * 32];
        bf16x8 b0 = *(const bf16x8*)&vT[(bj * 16 + l15) * 72 + l4 * 8 + kk * 32];
        ao0 = __builtin_amdgcn_mfma_f32_16x16x32_bf16(avv, b0, ao0, 0, 0, 0);
        bf16x8 b1 = *(const bf16x8*)&vT[((bj + 4) * 16 + l15) * 72 + l4 * 8 + kk * 32];
        ao1 = __builtin_amdgcn_mfma_f32_16x16x32_bf16(avv, b1, ao1, 0, 0, 0);
        if (bj == 0) {
          bf16x8 b2 = *(const bf16x8*)&vT[(128 + l15) * 72 + l4 * 8 + kk * 32];
          ao2 = __builtin_amdgcn_mfma_f32_16x16x32_bf16(avv, b2, ao2, 0, 0, 0);
        }
      }
    }
    // ---- partial row stats (b64 AW reads; zero-padding removes guards) ----
    {
      int rb = bi * 16 + l4 * 4;
      ushort4 aw0 = *(const ushort4*)&AW_T[(bj * 16 + l15) * 72 + rb];
      ushort4 aw1 = *(const ushort4*)&AW_T[((bj + 4) * 16 + l15) * 72 + rb];
      ushort4 aw2 = aw0;
      if (bj == 0) aw2 = *(const ushort4*)&AW_T[(128 + l15) * 72 + rb];
      unsigned short a0[4] = {aw0.x, aw0.y, aw0.z, aw0.w};
      unsigned short a1[4] = {aw1.x, aw1.y, aw1.z, aw1.w};
      unsigned short a2[4] = {aw2.x, aw2.y, aw2.z, aw2.w};
#pragma unroll
      for (int r = 0; r < 4; ++r) {
        float v0 = ao0[r], v1 = ao1[r];
        float s1 = v0 + v1;
        float s2 = v0 * v0 + v1 * v1;
        float sdt = v0 * b2f(a0[r]) + v1 * b2f(a1[r]);
        if (bj == 0) {
          float v2 = ao2[r];  // cols >=130 are zero (vT pad rows zeroed)
          s1 += v2; s2 += v2 * v2; sdt += v2 * b2f(a2[r]);
        }
#pragma unroll
        for (int msk = 1; msk <= 8; msk <<= 1) {
          s1 += __shfl_xor(s1, msk, 64);
          s2 += __shfl_xor(s2, msk, 64);
          sdt += __shfl_xor(sdt, msk, 64);
        }
        if (l15 == 0) {
          stred[w][l4 * 4 + r][0] = s1;
          stred[w][l4 * 4 + r][1] = s2;
          stred[w][l4 * 4 + r][2] = sdt;
        }
      }
    }
    if (tid < 64 && n < 63) coeffs(n + 1);   // hoisted: no extra barrier
    __syncthreads();  // D

    // ---- finalize (wave 0) ----
    if (tid < 64) {
      int row = tid, bnd = row >> 4, rr = row & 15;
      float s1 = 0.f, s2 = 0.f, sdt = 0.f;
#pragma unroll
      for (int jw = 0; jw < 4; ++jw) {
        s1  += stred[bnd * 4 + jw][rr][0];
        s2  += stred[bnd * 4 + jw][rr][1];
        sdt += stred[bnd * 4 + jw][rr][2];
      }
      float mz  = 2.f * s1 * (1.f / 130.f);
      float ez2 = 4.f * s2 * (1.f / 130.f);
      float sg  = sqrtf(fmaxf(ez2 - mz * mz, 0.f));
      float i2  = 1.f / (sg + EPSF);
      float val = (2.f * sdt - mz * Paw[row]) * i2;
#pragma unroll
      for (int msk = 1; msk <= 32; msk <<= 1) val += __shfl_xor(val, msk, 64);
      if (tid == 0) out[b * 64 + n] = val + ccv;
    }
  }
}

// ---------------- host launch ----------------
extern "C" void kernel_launch(void* const* d_in, const int* in_sizes, int n_in,
                              void* d_out, int out_size, void* d_ws, size_t ws_size,
                              hipStream_t stream) {
  const float* sp     = (const float*)d_in[0];
  const float* h1     = (const float*)d_in[1];
  const float* h2     = (const float*)d_in[2];
  const float* Wq     = (const float*)d_in[3];
  const float* bq     = (const float*)d_in[4];
  const float* Wk     = (const float*)d_in[5];
  const float* bk     = (const float*)d_in[6];
  const float* Wv     = (const float*)d_in[7];
  const float* bv     = (const float*)d_in[8];
  const float* alpha1 = (const float*)d_in[9];
  const float* beta1  = (const float*)d_in[10];
  const float* alpha2 = (const float*)d_in[11];
  const float* beta2  = (const float*)d_in[12];
  const float* Wlin   = (const float*)d_in[13];
  const float* blin   = (const float*)d_in[14];
  float* out = (float*)d_out;

  unsigned short* UqkB = (unsigned short*)d_ws;     // 256*2*64*136 = 4,456,448
  unsigned short* UvB  = UqkB + 4456448;            // 256*136*64   = 2,228,224
  unsigned short* ABqk = UvB + 2228224;             // 2*64*272     = 34,816
  unsigned short* ABv  = ABqk + 34816;              // 136*128      = 17,408
  unsigned short* AWt  = ABv + 17408;               // 144*72       = 10,368
  float* S1g = (float*)(AWt + 10368);               // 16384
  float* S2g = S1g + 16384;                         // 16384
  float* Paw = S2g + 16384;                         // 64
  float* Ccw = Paw + 64;                            // 1   -> total ~13.6 MB

  k0<<<dim3(7), dim3(256), 0, stream>>>(alpha1, beta1, alpha2, beta2,
                                        Wq, bq, Wk, bk, Wv, bv, Wlin, blin,
                                        ABqk, ABv, AWt, Paw, Ccw);
  k1<<<dim3(256), dim3(256), 0, stream>>>(h1, h2, sp, alpha1, Wq, Wk, Wv,
                                          UqkB, UvB, S1g, S2g);
  k2<<<dim3(256), dim3(1024), 0, stream>>>(h2, alpha1, UqkB, UvB, ABqk, ABv, AWt,
                                           S1g, S2g, Paw, Ccw,
                                           Wq, Wk, Wv, out);
}